// Round 2
// baseline (1184.200 us; speedup 1.0000x reference)
//
#include <hip/hip_runtime.h>
#include <cstdint>

#define CAP 32
#define OVF_MAX 65536

// ------------------------------------------------------------- degree+index build
__global__ __launch_bounds__(256) void scatter_k(const int* __restrict__ edge, int E,
        int* __restrict__ cnt, int* __restrict__ idx,
        int* __restrict__ ovf_cnt, int* __restrict__ ovf) {
    int e = blockIdx.x * blockDim.x + threadIdx.x;
    if (e >= E) return;
    int s = edge[e];           // row 0: src
    int d = edge[E + e];       // row 1: dst
    int slot = atomicAdd(&cnt[d], 1);
    if (slot < CAP) {
        idx[(int64_t)d * CAP + slot] = s;
    } else {
        int o = atomicAdd(ovf_cnt, 1);
        if (o < OVF_MAX) { ovf[2 * o] = s; ovf[2 * o + 1] = d; }
    }
}

// ------------------------------------------------------------- fused SAGE layer
// Per block: 16 nodes. Phase A: stage x rows (sX) + gather-mean neighbors (sA).
// Phase B: register-tiled GEMM  out = relu(sA@Wl + bl + sX@Wr)  [+res, +head dot]
// Thread layout phase B: wave wv (0..3) -> rows wv*4..wv*4+3; lane -> cols lane, lane+64.
// D=144: src0 = x (N x 128), src1 = emb (N x 16).  D=128: src0 = h1.
template<int D, bool HEAD, bool ACCUM>
__global__ __launch_bounds__(256) void fused_sage(
        const float* __restrict__ src0, const float* __restrict__ src1,
        const int* __restrict__ idx, const int* __restrict__ cnt,
        const int* __restrict__ ovfc, const int* __restrict__ ovf,
        const float* __restrict__ Wl, const float* __restrict__ bl,
        const float* __restrict__ Wr,
        float* __restrict__ hout,                  // !HEAD: [N,128] output
        float* __restrict__ dout,                  // HEAD: [N] output
        const float* __restrict__ Wseg, const float* __restrict__ linb,
        int N) {
    __shared__ float sA[16 * D];
    __shared__ float sX[16 * D];
    const int tid = threadIdx.x;
    const int lane = tid & 63;
    const int wv = tid >> 6;
    const int64_t block0 = (int64_t)blockIdx.x * 16;
    const int nrows = (int)min((int64_t)16, (int64_t)N - block0);

    // ---- stage own rows into sX (vectorized)
    constexpr int Q = D / 4;                       // float4 per row: 36 or 32
    for (int f = tid; f < 16 * Q; f += 256) {
        int r = f / Q, q = f - r * Q;
        if (r < nrows) {
            int64_t row = block0 + r;
            float4 v;
            if (D == 144) {
                if (q < 32) v = reinterpret_cast<const float4*>(src0)[row * 32 + q];
                else        v = reinterpret_cast<const float4*>(src1)[row * 4 + (q - 32)];
            } else {
                v = reinterpret_cast<const float4*>(src0)[row * 32 + q];
            }
            reinterpret_cast<float4*>(sX)[f] = v;
        }
    }

    // ---- gather-mean 4 nodes per wave into sA
    for (int j = 0; j < 4; ++j) {
        int r = wv * 4 + j;
        int64_t i = block0 + r;
        if (i < N) {                               // wave-uniform
            int craw = cnt[i];
            int c = min(craw, CAP);
            const int* ip = idx + i * CAP;
            int myid = (lane < c) ? ip[lane] : 0;  // one coalesced load of all ids
            float a0 = 0.f, a1 = 0.f, a2 = 0.f;
            for (int k = 0; k < c; ++k) {
                int s = __builtin_amdgcn_readlane(myid, k);
                const float* xr = src0 + (int64_t)s * 128;
                a0 += xr[lane];
                a1 += xr[64 + lane];
                if (D == 144) { if (lane < 16) a2 += src1[(int64_t)s * 16 + lane]; }
            }
            if (craw > CAP) {                      // rare overflow fixup
                int novf = min(ovfc[0], OVF_MAX);
                for (int e = 0; e < novf; ++e) {
                    if (ovf[2 * e + 1] == (int)i) {
                        int s = ovf[2 * e];
                        const float* xr = src0 + (int64_t)s * 128;
                        a0 += xr[lane];
                        a1 += xr[64 + lane];
                        if (D == 144) { if (lane < 16) a2 += src1[(int64_t)s * 16 + lane]; }
                    }
                }
            }
            float rinv = 1.0f / fmaxf((float)craw, 1.0f);
            sA[r * D + lane] = a0 * rinv;
            sA[r * D + 64 + lane] = a1 * rinv;
            if (D == 144) { if (lane < 16) sA[r * D + 128 + lane] = a2 * rinv; }
        }
    }
    __syncthreads();

    // ---- GEMM
    const int tx = lane;
    float accL[4][2] = {{0,0},{0,0},{0,0},{0,0}};
    float accR[4][2] = {{0,0},{0,0},{0,0},{0,0}};
    for (int k = 0; k < D; k += 4) {
        float4 a4[4], x4[4];
        #pragma unroll
        for (int m = 0; m < 4; ++m) {
            a4[m] = *reinterpret_cast<const float4*>(&sA[(wv * 4 + m) * D + k]);
            x4[m] = *reinterpret_cast<const float4*>(&sX[(wv * 4 + m) * D + k]);
        }
        #pragma unroll
        for (int kk = 0; kk < 4; ++kk) {
            float wl0 = Wl[(k + kk) * 128 + tx];
            float wl1 = Wl[(k + kk) * 128 + 64 + tx];
            float wr0 = Wr[(k + kk) * 128 + tx];
            float wr1 = Wr[(k + kk) * 128 + 64 + tx];
            #pragma unroll
            for (int m = 0; m < 4; ++m) {
                float av = (&a4[m].x)[kk];
                float xv = (&x4[m].x)[kk];
                accL[m][0] = fmaf(av, wl0, accL[m][0]);
                accL[m][1] = fmaf(av, wl1, accL[m][1]);
                accR[m][0] = fmaf(xv, wr0, accR[m][0]);
                accR[m][1] = fmaf(xv, wr1, accR[m][1]);
            }
        }
    }

    float b0 = bl[tx], b1 = bl[64 + tx];
    if (!HEAD) {
        #pragma unroll
        for (int m = 0; m < 4; ++m) {
            int r = wv * 4 + m;
            if (r < nrows) {
                int64_t row = block0 + r;
                float vL = fmaxf(accL[m][0] + accR[m][0] + b0, 0.f);
                float vR = fmaxf(accL[m][1] + accR[m][1] + b1, 0.f);
                hout[row * 128 + tx] = vL;
                hout[row * 128 + 64 + tx] = vR;
            }
        }
    } else {
        // layer-2: residual (+h1 staged in sX) then head partial dot
        float w0 = Wseg[tx], w1 = Wseg[64 + tx];
        #pragma unroll
        for (int m = 0; m < 4; ++m) {
            int r = wv * 4 + m;
            float vL = fmaxf(accL[m][0] + accR[m][0] + b0, 0.f) + sX[r * D + tx];
            float vR = fmaxf(accL[m][1] + accR[m][1] + b1, 0.f) + sX[r * D + 64 + tx];
            float p = vL * w0 + vR * w1;
            #pragma unroll
            for (int o = 32; o > 0; o >>= 1) p += __shfl_xor(p, o, 64);
            if (lane == 0 && r < nrows) {
                int64_t row = block0 + r;
                float val = p;
                if (ACCUM) val += dout[row] + linb[0];
                dout[row] = val;
            }
        }
    }
}

// ------------------------------------------------------------- launch
extern "C" void kernel_launch(void* const* d_in, const int* in_sizes, int n_in,
                              void* d_out, int out_size, void* d_ws, size_t ws_size,
                              hipStream_t stream) {
    const float* x       = (const float*)d_in[0];
    const int*   edge_in = (const int*)d_in[1];
    const int*   edge_out= (const int*)d_in[2];
    const float* emb     = (const float*)d_in[3];
    const float* in1_Wl  = (const float*)d_in[4];
    const float* in1_bl  = (const float*)d_in[5];
    const float* in1_Wr  = (const float*)d_in[6];
    const float* in2_Wl  = (const float*)d_in[7];
    const float* in2_bl  = (const float*)d_in[8];
    const float* in2_Wr  = (const float*)d_in[9];
    const float* out1_Wl = (const float*)d_in[10];
    const float* out1_bl = (const float*)d_in[11];
    const float* out1_Wr = (const float*)d_in[12];
    const float* out2_Wl = (const float*)d_in[13];
    const float* out2_bl = (const float*)d_in[14];
    const float* out2_Wr = (const float*)d_in[15];
    const float* lin_W   = (const float*)d_in[16];
    const float* lin_b   = (const float*)d_in[17];

    const int N = in_sizes[0] / 128;
    const int E = in_sizes[1] / 2;

    // workspace (~65 MB total; round-0 crash was ~270 MB -> suspected ws overflow)
    char* wsb = (char*)d_ws;
    size_t off = 0;
    auto alloc = [&](size_t bytes) {
        char* p = wsb + off;
        off = (off + bytes + 255) & ~(size_t)255;
        return p;
    };
    int*   idx  = (int*)alloc((size_t)N * CAP * 4);      // 12.8 MB
    int*   cnt  = (int*)alloc((size_t)N * 4);            //  0.4 MB
    int*   ovfc = (int*)alloc(256);
    int*   ovf  = (int*)alloc((size_t)OVF_MAX * 2 * 4);  //  0.5 MB
    float* h1   = (float*)alloc((size_t)N * 128 * 4);    // 51.2 MB

    const int sg = (E + 255) / 256;
    const int fg = (N + 15) / 16;

    // ---- OUT direction (writes d_out = s_out)
    hipMemsetAsync(cnt, 0, (size_t)N * 4, stream);
    hipMemsetAsync(ovfc, 0, 4, stream);
    scatter_k<<<sg, 256, 0, stream>>>(edge_out, E, cnt, idx, ovfc, ovf);
    fused_sage<144, false, false><<<fg, 256, 0, stream>>>(x, emb, idx, cnt, ovfc, ovf,
            out1_Wl, out1_bl, out1_Wr, h1, nullptr, nullptr, nullptr, N);
    fused_sage<128, true, false><<<fg, 256, 0, stream>>>(h1, nullptr, idx, cnt, ovfc, ovf,
            out2_Wl, out2_bl, out2_Wr, nullptr, (float*)d_out, lin_W + 128, lin_b, N);

    // ---- IN direction (accumulates d_out += s_in + b)
    hipMemsetAsync(cnt, 0, (size_t)N * 4, stream);
    hipMemsetAsync(ovfc, 0, 4, stream);
    scatter_k<<<sg, 256, 0, stream>>>(edge_in, E, cnt, idx, ovfc, ovf);
    fused_sage<144, false, false><<<fg, 256, 0, stream>>>(x, emb, idx, cnt, ovfc, ovf,
            in1_Wl, in1_bl, in1_Wr, h1, nullptr, nullptr, nullptr, N);
    fused_sage<128, true, true><<<fg, 256, 0, stream>>>(h1, nullptr, idx, cnt, ovfc, ovf,
            in2_Wl, in2_bl, in2_Wr, nullptr, (float*)d_out, lin_W, lin_b, N);
}

// Round 3
// 778.157 us; speedup vs baseline: 1.5218x; 1.5218x over previous
//
#include <hip/hip_runtime.h>
#include <hip/hip_bf16.h>
#include <cstdint>

using u16 = unsigned short;
using u32 = unsigned int;
using bf16x8 = __attribute__((ext_vector_type(8))) short;
using f32x4  = __attribute__((ext_vector_type(4))) float;

__device__ __forceinline__ float b2f(u16 b) { return __uint_as_float(((u32)b) << 16); }
__device__ __forceinline__ u16 f2b(float f) {
    u32 u = __float_as_uint(f);
    return (u16)((u + 0x7fff + ((u >> 16) & 1)) >> 16);   // RNE
}

// ---------------------------------------------------------------- xb = [x|emb] bf16
__global__ __launch_bounds__(256) void build_xb_k(const float* __restrict__ x,
        const float* __restrict__ emb, u16* __restrict__ xb, int N) {
    int t = blockIdx.x * 256 + threadIdx.x;
    if (t >= N * 36) return;
    int i = t / 36, q = t - i * 36;
    float4 v = (q < 32) ? reinterpret_cast<const float4*>(x)[(int64_t)i * 32 + q]
                        : reinterpret_cast<const float4*>(emb)[(int64_t)i * 4 + (q - 32)];
    u32 lo = (u32)f2b(v.x) | ((u32)f2b(v.y) << 16);
    u32 hi = (u32)f2b(v.z) | ((u32)f2b(v.w) << 16);
    *reinterpret_cast<uint2*>(xb + (int64_t)i * 144 + q * 4) = make_uint2(lo, hi);
}

// ---------------------------------------------------------------- weight B-fragment pack
// wp element (kt,nt,lane,j) = Wcat[kt*32+(lane>>4)*8+j][nt*16+(lane&15)], Wcat=[Wl;Wr]
template<int D>
__global__ __launch_bounds__(256) void pack_w_k(const float* __restrict__ Wl,
        const float* __restrict__ Wr, u16* __restrict__ wp) {
    constexpr int KT = (2 * D) / 32;
    int gid = blockIdx.x * 256 + threadIdx.x;
    if (gid >= KT * 8 * 64) return;
    int lane = gid & 63, nt = (gid >> 6) & 7, kt = gid >> 9;
    int n = nt * 16 + (lane & 15);
    int kb = kt * 32 + ((lane >> 4) & 3) * 8;
    u32 out[4];
    #pragma unroll
    for (int jj = 0; jj < 4; ++jj) {
        int k0 = kb + 2 * jj, k1 = k0 + 1;
        float f0 = (k0 < D) ? Wl[k0 * 128 + n] : Wr[(k0 - D) * 128 + n];
        float f1 = (k1 < D) ? Wl[k1 * 128 + n] : Wr[(k1 - D) * 128 + n];
        out[jj] = (u32)f2b(f0) | ((u32)f2b(f1) << 16);
    }
    *reinterpret_cast<uint4*>(wp + (size_t)gid * 8) = make_uint4(out[0], out[1], out[2], out[3]);
}

// ---------------------------------------------------------------- CSR build
__global__ __launch_bounds__(256) void count_k(const int* __restrict__ edge, int E,
        int* __restrict__ cnt) {
    int e = blockIdx.x * 256 + threadIdx.x;
    if (e < E) atomicAdd(&cnt[edge[E + e]], 1);
}
#define SCAN_TILE 1024
__global__ __launch_bounds__(256) void scan_sum_k(const int* __restrict__ cnt, int N,
        int* __restrict__ bsum) {
    __shared__ int sred[256];
    int s = 0;
    for (int t = threadIdx.x; t < SCAN_TILE; t += 256) {
        int i = blockIdx.x * SCAN_TILE + t;
        s += (i < N) ? cnt[i] : 0;
    }
    sred[threadIdx.x] = s; __syncthreads();
    for (int off = 128; off > 0; off >>= 1) {
        if (threadIdx.x < off) sred[threadIdx.x] += sred[threadIdx.x + off];
        __syncthreads();
    }
    if (threadIdx.x == 0) bsum[blockIdx.x] = sred[0];
}
__global__ void scan_carry_k(int* bsum, int nb, int* rpN) {
    if (threadIdx.x == 0) {
        int run = 0;
        for (int b = 0; b < nb; ++b) { int v = bsum[b]; bsum[b] = run; run += v; }
        rpN[0] = run;
    }
}
__global__ __launch_bounds__(256) void scan_write_k(const int* __restrict__ cnt, int N,
        const int* __restrict__ bsum, int* __restrict__ rp) {
    __shared__ int sth[256];
    int tid = threadIdx.x;
    int i0 = blockIdx.x * SCAN_TILE + tid * 4;
    int vals[4]; int loc = 0;
    #pragma unroll
    for (int q = 0; q < 4; ++q) { int i = i0 + q; vals[q] = (i < N) ? cnt[i] : 0; loc += vals[q]; }
    sth[tid] = loc; __syncthreads();
    for (int off = 1; off < 256; off <<= 1) {
        int y = (tid >= off) ? sth[tid - off] : 0;
        __syncthreads();
        sth[tid] += y;
        __syncthreads();
    }
    int excl = sth[tid] - loc + bsum[blockIdx.x];
    #pragma unroll
    for (int q = 0; q < 4; ++q) { int i = i0 + q; if (i < N) rp[i] = excl; excl += vals[q]; }
}
__global__ __launch_bounds__(256) void fill_k(const int* __restrict__ edge, int E,
        const int* __restrict__ rp, int* __restrict__ cur, int* __restrict__ colv) {
    int e = blockIdx.x * 256 + threadIdx.x;
    if (e >= E) return;
    int s = edge[e], d = edge[E + e];
    colv[rp[d] + atomicAdd(&cur[d], 1)] = s;
}

// ---------------------------------------------------------------- fused SAGE layer
// 16 nodes/block. Phase A: gather-mean (bf16 rows, f32 accum) into LDS k[0..D) and
// stage self rows into k[D..2D). Phase B: MFMA GEMM vs packed [Wl;Wr], K=2D.
// HEAD: +residual (self row), head partial dot, write/accumulate scalar d_out.
template<int D, bool HEAD, bool ACCUM>
__global__ __launch_bounds__(256) void fused_sage(
        const u16* __restrict__ src,                // bf16 table [N][D]
        const int* __restrict__ rp, const int* __restrict__ colv,
        const u16* __restrict__ wp, const float* __restrict__ bl,
        u16* __restrict__ hout, float* __restrict__ dout,
        const float* __restrict__ Wseg, const float* __restrict__ linb, int N) {
    constexpr int K = 2 * D;
    constexpr int KT = K / 32;
    constexpr int ROWB = 592;                        // LDS row stride bytes (37*16, ~2-way banks)
    __shared__ u16 sAB[16 * (ROWB / 2)];
    __shared__ float ps[4][16];
    const int tid = threadIdx.x;
    const int lane = tid & 63;
    const int wv = tid >> 6;
    const int64_t block0 = (int64_t)blockIdx.x * 16;
    const int nrows = (int)min((int64_t)16, (int64_t)N - block0);

    // ---- stage self rows at k offset D
    constexpr int CH = D / 8;                        // 16B chunks per row
    for (int f = tid; f < 16 * CH; f += 256) {
        int r = f / CH, q = f - r * CH;
        if (r < nrows) {
            uint4 v = reinterpret_cast<const uint4*>(src + (block0 + r) * D)[q];
            *reinterpret_cast<uint4*>((char*)sAB + r * ROWB + D * 2 + q * 16) = v;
        }
    }

    // ---- gather-mean: wave handles 4 nodes; 2 neighbors in flight (32 lanes each)
    const int g = lane >> 5;
    const int hl = lane & 31;
    for (int j = 0; j < 4; ++j) {
        int r = wv * 4 + j;
        int64_t i = block0 + r;
        if (i >= N) continue;                        // wave-uniform
        int base = rp[i];
        int deg = rp[i + 1] - base;
        float a0 = 0.f, a1 = 0.f, a2 = 0.f, a3 = 0.f, e0 = 0.f, e1 = 0.f;
        for (int ch = 0; ch < deg; ch += 32) {
            int cc = min(32, deg - ch);
            int myid = (lane < cc) ? colv[base + ch + lane] : 0;
            for (int k = 0; k < cc; k += 2) {
                int kk = k + g;
                bool valid = kk < cc;
                int s = __shfl(myid, valid ? kk : 0, 64);
                const u16* xr = src + (int64_t)s * D;
                if (valid) {
                    uint2 m = *reinterpret_cast<const uint2*>(xr + hl * 4);
                    a0 += b2f((u16)(m.x & 0xffffu)); a1 += b2f((u16)(m.x >> 16));
                    a2 += b2f((u16)(m.y & 0xffffu)); a3 += b2f((u16)(m.y >> 16));
                    if (D == 144) {
                        if (hl < 8) {
                            u32 e = *reinterpret_cast<const u32*>(xr + 128 + hl * 2);
                            e0 += b2f((u16)(e & 0xffffu)); e1 += b2f((u16)(e >> 16));
                        }
                    }
                }
            }
        }
        a0 += __shfl_xor(a0, 32, 64); a1 += __shfl_xor(a1, 32, 64);
        a2 += __shfl_xor(a2, 32, 64); a3 += __shfl_xor(a3, 32, 64);
        if (D == 144) { e0 += __shfl_xor(e0, 32, 64); e1 += __shfl_xor(e1, 32, 64); }
        float rinv = 1.0f / fmaxf((float)deg, 1.0f);
        char* rowp = (char*)sAB + r * ROWB;
        if (lane < 32) {
            u32 lo = (u32)f2b(a0 * rinv) | ((u32)f2b(a1 * rinv) << 16);
            u32 hi = (u32)f2b(a2 * rinv) | ((u32)f2b(a3 * rinv) << 16);
            *reinterpret_cast<uint2*>(rowp + hl * 8) = make_uint2(lo, hi);
            if (D == 144) {
                if (hl < 8) {
                    u32 ev = (u32)f2b(e0 * rinv) | ((u32)f2b(e1 * rinv) << 16);
                    *reinterpret_cast<u32*>(rowp + 256 + hl * 4) = ev;
                }
            }
        }
    }
    __syncthreads();

    // ---- MFMA GEMM: wave wv covers n-tiles {2wv, 2wv+1}, all 16 rows, K=2D
    const int arow = lane & 15;
    const int kgrp = (lane >> 4) & 3;
    const int nt0 = wv * 2;
    f32x4 acc0 = {0.f, 0.f, 0.f, 0.f}, acc1 = {0.f, 0.f, 0.f, 0.f};
    for (int kt = 0; kt < KT; ++kt) {
        bf16x8 a = *reinterpret_cast<const bf16x8*>((char*)sAB + arow * ROWB + kt * 64 + kgrp * 16);
        bf16x8 b0 = *reinterpret_cast<const bf16x8*>(wp + ((size_t)(kt * 8 + nt0) * 64 + lane) * 8);
        bf16x8 b1 = *reinterpret_cast<const bf16x8*>(wp + ((size_t)(kt * 8 + nt0 + 1) * 64 + lane) * 8);
        acc0 = __builtin_amdgcn_mfma_f32_16x16x32_bf16(a, b0, acc0, 0, 0, 0);
        acc1 = __builtin_amdgcn_mfma_f32_16x16x32_bf16(a, b1, acc1, 0, 0, 0);
    }

    float bias0 = bl[nt0 * 16 + arow], bias1 = bl[nt0 * 16 + 16 + arow];
    if (!HEAD) {
        #pragma unroll
        for (int q = 0; q < 4; ++q) {
            int r = kgrp * 4 + q;
            if (r < nrows) {
                int64_t row = block0 + r;
                hout[row * 128 + nt0 * 16 + arow]      = f2b(fmaxf(acc0[q] + bias0, 0.f));
                hout[row * 128 + nt0 * 16 + 16 + arow] = f2b(fmaxf(acc1[q] + bias1, 0.f));
            }
        }
    } else {
        float w0 = Wseg[nt0 * 16 + arow], w1 = Wseg[nt0 * 16 + 16 + arow];
        float p[4];
        #pragma unroll
        for (int q = 0; q < 4; ++q) {
            int r = kgrp * 4 + q;
            const u16* selfrow = (const u16*)((char*)sAB + r * ROWB + D * 2);
            float v0 = fmaxf(acc0[q] + bias0, 0.f) + b2f(selfrow[nt0 * 16 + arow]);
            float v1 = fmaxf(acc1[q] + bias1, 0.f) + b2f(selfrow[nt0 * 16 + 16 + arow]);
            p[q] = v0 * w0 + v1 * w1;
        }
        #pragma unroll
        for (int off = 1; off < 16; off <<= 1) {
            p[0] += __shfl_xor(p[0], off, 64);
            p[1] += __shfl_xor(p[1], off, 64);
            p[2] += __shfl_xor(p[2], off, 64);
            p[3] += __shfl_xor(p[3], off, 64);
        }
        if (arow == 0) {
            #pragma unroll
            for (int q = 0; q < 4; ++q) ps[wv][kgrp * 4 + q] = p[q];
        }
        __syncthreads();
        if (tid < 16 && tid < nrows) {
            float s = ps[0][tid] + ps[1][tid] + ps[2][tid] + ps[3][tid];
            int64_t row = block0 + tid;
            if (ACCUM) dout[row] += s + linb[0];
            else dout[row] = s;
        }
    }
}

// ---------------------------------------------------------------- launch
extern "C" void kernel_launch(void* const* d_in, const int* in_sizes, int n_in,
                              void* d_out, int out_size, void* d_ws, size_t ws_size,
                              hipStream_t stream) {
    const float* x       = (const float*)d_in[0];
    const int*   edge_in = (const int*)d_in[1];
    const int*   edge_out= (const int*)d_in[2];
    const float* emb     = (const float*)d_in[3];
    const float* in1_Wl  = (const float*)d_in[4];
    const float* in1_bl  = (const float*)d_in[5];
    const float* in1_Wr  = (const float*)d_in[6];
    const float* in2_Wl  = (const float*)d_in[7];
    const float* in2_bl  = (const float*)d_in[8];
    const float* in2_Wr  = (const float*)d_in[9];
    const float* out1_Wl = (const float*)d_in[10];
    const float* out1_bl = (const float*)d_in[11];
    const float* out1_Wr = (const float*)d_in[12];
    const float* out2_Wl = (const float*)d_in[13];
    const float* out2_bl = (const float*)d_in[14];
    const float* out2_Wr = (const float*)d_in[15];
    const float* lin_W   = (const float*)d_in[16];
    const float* lin_b   = (const float*)d_in[17];

    const int N = in_sizes[0] / 128;
    const int E = in_sizes[1] / 2;
    const int nb = (N + SCAN_TILE - 1) / SCAN_TILE;

    char* wsb = (char*)d_ws;
    size_t off = 0;
    auto alloc = [&](size_t bytes) {
        char* p = wsb + off;
        off = (off + bytes + 255) & ~(size_t)255;
        return p;
    };
    int* rp    = (int*)alloc((size_t)(N + 1) * 4);       //  0.4 MB
    int* cnt   = (int*)alloc((size_t)N * 4);             //  0.4 MB
    int* colv  = (int*)alloc((size_t)E * 4);             //  6.4 MB
    int* bsum  = (int*)alloc((size_t)(nb + 1) * 4);
    u16* xb    = (u16*)alloc((size_t)N * 144 * 2);       // 28.8 MB
    u16* h1b   = (u16*)alloc((size_t)N * 128 * 2);       // 25.6 MB
    u16* wp_i1 = (u16*)alloc((size_t)288 * 128 * 2);
    u16* wp_i2 = (u16*)alloc((size_t)256 * 128 * 2);
    u16* wp_o1 = (u16*)alloc((size_t)288 * 128 * 2);
    u16* wp_o2 = (u16*)alloc((size_t)256 * 128 * 2);     // total ~62 MB

    build_xb_k<<<(N * 36 + 255) / 256, 256, 0, stream>>>(x, emb, xb, N);
    pack_w_k<144><<<18, 256, 0, stream>>>(in1_Wl, in1_Wr, wp_i1);
    pack_w_k<128><<<16, 256, 0, stream>>>(in2_Wl, in2_Wr, wp_i2);
    pack_w_k<144><<<18, 256, 0, stream>>>(out1_Wl, out1_Wr, wp_o1);
    pack_w_k<128><<<16, 256, 0, stream>>>(out2_Wl, out2_Wr, wp_o2);

    const int eg = (E + 255) / 256;
    const int fg = (N + 15) / 16;

    auto build_csr = [&](const int* edge) {
        hipMemsetAsync(cnt, 0, (size_t)N * 4, stream);
        count_k<<<eg, 256, 0, stream>>>(edge, E, cnt);
        scan_sum_k<<<nb, 256, 0, stream>>>(cnt, N, bsum);
        scan_carry_k<<<1, 64, 0, stream>>>(bsum, nb, rp + N);
        scan_write_k<<<nb, 256, 0, stream>>>(cnt, N, bsum, rp);
        hipMemsetAsync(cnt, 0, (size_t)N * 4, stream);
        fill_k<<<eg, 256, 0, stream>>>(edge, E, rp, cnt, colv);
    };

    // ---- OUT direction: d_out = s_out
    build_csr(edge_out);
    fused_sage<144, false, false><<<fg, 256, 0, stream>>>(xb, rp, colv, wp_o1, out1_bl,
            h1b, nullptr, nullptr, nullptr, N);
    fused_sage<128, true, false><<<fg, 256, 0, stream>>>(h1b, rp, colv, wp_o2, out2_bl,
            nullptr, (float*)d_out, lin_W + 128, lin_b, N);

    // ---- IN direction: d_out += s_in + b
    build_csr(edge_in);
    fused_sage<144, false, false><<<fg, 256, 0, stream>>>(xb, rp, colv, wp_i1, in1_bl,
            h1b, nullptr, nullptr, nullptr, N);
    fused_sage<128, true, true><<<fg, 256, 0, stream>>>(h1b, rp, colv, wp_i2, in2_bl,
            nullptr, (float*)d_out, lin_W, lin_b, N);
}

// Round 4
// 758.558 us; speedup vs baseline: 1.5611x; 1.0258x over previous
//
#include <hip/hip_runtime.h>
#include <cstdint>

using u16 = unsigned short;
using u32 = unsigned int;
using bf16x8 = __attribute__((ext_vector_type(8))) short;
using f32x4  = __attribute__((ext_vector_type(4))) float;

__device__ __forceinline__ float b2f(u16 b) { return __uint_as_float(((u32)b) << 16); }
__device__ __forceinline__ u16 f2b(float f) {
    u32 u = __float_as_uint(f);
    return (u16)((u + 0x7fff + ((u >> 16) & 1)) >> 16);   // RNE
}

// ---------------------------------------------------------------- xb = [x|emb] bf16
__global__ __launch_bounds__(256) void build_xb_k(const float* __restrict__ x,
        const float* __restrict__ emb, u16* __restrict__ xb, int N) {
    int t = blockIdx.x * 256 + threadIdx.x;
    if (t >= N * 36) return;
    int i = t / 36, q = t - i * 36;
    float4 v = (q < 32) ? reinterpret_cast<const float4*>(x)[(int64_t)i * 32 + q]
                        : reinterpret_cast<const float4*>(emb)[(int64_t)i * 4 + (q - 32)];
    u32 lo = (u32)f2b(v.x) | ((u32)f2b(v.y) << 16);
    u32 hi = (u32)f2b(v.z) | ((u32)f2b(v.w) << 16);
    *reinterpret_cast<uint2*>(xb + (int64_t)i * 144 + q * 4) = make_uint2(lo, hi);
}

// ---------------------------------------------------------------- weight B-fragment pack
// wp element (kt,nt,lane,j) = Wcat[kt*32+(lane>>4)*8+j][nt*16+(lane&15)], Wcat=[Wl;Wr]
template<int D>
__global__ __launch_bounds__(256) void pack_w_k(const float* __restrict__ Wl,
        const float* __restrict__ Wr, u16* __restrict__ wp) {
    constexpr int KT = (2 * D) / 32;
    int gid = blockIdx.x * 256 + threadIdx.x;
    if (gid >= KT * 8 * 64) return;
    int lane = gid & 63, nt = (gid >> 6) & 7, kt = gid >> 9;
    int n = nt * 16 + (lane & 15);
    int kb = kt * 32 + ((lane >> 4) & 3) * 8;
    u32 out[4];
    #pragma unroll
    for (int jj = 0; jj < 4; ++jj) {
        int k0 = kb + 2 * jj, k1 = k0 + 1;
        float f0 = (k0 < D) ? Wl[k0 * 128 + n] : Wr[(k0 - D) * 128 + n];
        float f1 = (k1 < D) ? Wl[k1 * 128 + n] : Wr[(k1 - D) * 128 + n];
        out[jj] = (u32)f2b(f0) | ((u32)f2b(f1) << 16);
    }
    *reinterpret_cast<uint4*>(wp + (size_t)gid * 8) = make_uint4(out[0], out[1], out[2], out[3]);
}

// ---------------------------------------------------------------- bucket build
// bucket b = 16 dst nodes = one fused_sage block
__global__ __launch_bounds__(256) void bcount_k(const int* __restrict__ edge, int E,
        int* __restrict__ bcnt) {
    int e = blockIdx.x * 256 + threadIdx.x;
    if (e < E) atomicAdd(&bcnt[edge[E + e] >> 4], 1);
}

#define SCAN_TILE 1024
__global__ __launch_bounds__(256) void scan_sum_k(const int* __restrict__ cnt, int N,
        int* __restrict__ bsum) {
    __shared__ int sred[256];
    int s = 0;
    for (int t = threadIdx.x; t < SCAN_TILE; t += 256) {
        int i = blockIdx.x * SCAN_TILE + t;
        s += (i < N) ? cnt[i] : 0;
    }
    sred[threadIdx.x] = s; __syncthreads();
    for (int off = 128; off > 0; off >>= 1) {
        if (threadIdx.x < off) sred[threadIdx.x] += sred[threadIdx.x + off];
        __syncthreads();
    }
    if (threadIdx.x == 0) bsum[blockIdx.x] = sred[0];
}
__global__ void scan_carry_k(int* bsum, int nb, int* rpN) {
    if (threadIdx.x == 0) {
        int run = 0;
        for (int b = 0; b < nb; ++b) { int v = bsum[b]; bsum[b] = run; run += v; }
        rpN[0] = run;
    }
}
__global__ __launch_bounds__(256) void scan_write_k(const int* __restrict__ cnt, int N,
        const int* __restrict__ bsum, int* __restrict__ rp) {
    __shared__ int sth[256];
    int tid = threadIdx.x;
    int i0 = blockIdx.x * SCAN_TILE + tid * 4;
    int vals[4]; int loc = 0;
    #pragma unroll
    for (int q = 0; q < 4; ++q) { int i = i0 + q; vals[q] = (i < N) ? cnt[i] : 0; loc += vals[q]; }
    sth[tid] = loc; __syncthreads();
    for (int off = 1; off < 256; off <<= 1) {
        int y = (tid >= off) ? sth[tid - off] : 0;
        __syncthreads();
        sth[tid] += y;
        __syncthreads();
    }
    int excl = sth[tid] - loc + bsum[blockIdx.x];
    #pragma unroll
    for (int q = 0; q < 4; ++q) { int i = i0 + q; if (i < N) rp[i] = excl; excl += vals[q]; }
}

// rec = (dst&15)<<27 | src   (src < 2^27)
__global__ __launch_bounds__(256) void bscatter_k(const int* __restrict__ edge, int E,
        const int* __restrict__ brp, int* __restrict__ bcur, u32* __restrict__ recs) {
    int e = blockIdx.x * 256 + threadIdx.x;
    if (e >= E) return;
    int s = edge[e], d = edge[E + e];
    int b = d >> 4;
    int pos = brp[b] + atomicAdd(&bcur[b], 1);
    recs[pos] = ((u32)(d & 15) << 27) | (u32)s;
}

// ---------------------------------------------------------------- fused SAGE layer
// Block = bucket of 16 nodes. Phase A: chunked LDS counting-sort of edge records into
// per-node src lists; wave-gather bf16 rows (depth-2 pipelined), f32 accumulate;
// write mean rows (bf16) into LDS k[0..D) and self rows at k[D..2D).
// Phase B: MFMA GEMM vs packed [Wl;Wr], K=2D. HEAD: +residual, head dot, scalar out.
template<int D, bool HEAD, bool ACCUM>
__global__ __launch_bounds__(256) void fused_sage(
        const u16* __restrict__ src,                 // bf16 table [N][D]
        const int* __restrict__ brp, const u32* __restrict__ recs,
        const u16* __restrict__ wp, const float* __restrict__ bl,
        u16* __restrict__ hout, float* __restrict__ dout,
        const float* __restrict__ Wseg, const float* __restrict__ linb, int N) {
    constexpr int K = 2 * D;
    constexpr int KT = K / 32;
    constexpr int ROWB = 592;                        // LDS row stride bytes
    constexpr int CHUNK = 512;
    __shared__ u16 sAB[16 * (ROWB / 2)];
    __shared__ u32 rbuf[CHUNK];
    __shared__ u32 slist[CHUNK];
    __shared__ int ncnt[16], nrp[16], ncur[16], ndeg[16];
    __shared__ float ps[4][16];
    const int tid = threadIdx.x;
    const int lane = tid & 63;
    const int wv = tid >> 6;
    const int g = lane >> 5;                         // half-wave id
    const int hl = lane & 31;
    const int64_t block0 = (int64_t)blockIdx.x * 16;
    const int nrows = (int)min((int64_t)16, (int64_t)N - block0);

    // ---- stage self rows at k offset D
    constexpr int CH = D / 8;
    for (int f = tid; f < 16 * CH; f += 256) {
        int r = f / CH, q = f - r * CH;
        if (r < nrows) {
            uint4 v = reinterpret_cast<const uint4*>(src + (block0 + r) * D)[q];
            *reinterpret_cast<uint4*>((char*)sAB + r * ROWB + D * 2 + q * 16) = v;
        }
    }
    if (tid < 16) ndeg[tid] = 0;

    const int r0 = brp[blockIdx.x], r1 = brp[blockIdx.x + 1];
    float acc[4][4] = {{0,0,0,0},{0,0,0,0},{0,0,0,0},{0,0,0,0}};
    float ecc[4][2] = {{0,0},{0,0},{0,0},{0,0}};

    for (int base = r0; base < r1; base += CHUNK) {
        const int n = min(CHUNK, r1 - base);
        __syncthreads();                             // prev-chunk readers done
        for (int t = tid; t < n; t += 256) rbuf[t] = recs[base + t];
        if (tid < 16) ncnt[tid] = 0;
        __syncthreads();
        for (int t = tid; t < n; t += 256) atomicAdd(&ncnt[rbuf[t] >> 27], 1);
        __syncthreads();
        if (tid == 0) {
            int run = 0;
            #pragma unroll
            for (int i = 0; i < 16; ++i) { nrp[i] = run; run += ncnt[i]; }
        }
        if (tid < 16) { ncur[tid] = 0; ndeg[tid] += ncnt[tid]; }
        __syncthreads();
        for (int t = tid; t < n; t += 256) {
            u32 rc = rbuf[t];
            int dl = rc >> 27;
            slist[nrp[dl] + atomicAdd(&ncur[dl], 1)] = rc & 0x07ffffffu;
        }
        __syncthreads();
        // ---- gather: wave handles nodes wv*4..wv*4+3; two 32-lane groups, depth-2 pipeline
        #pragma unroll
        for (int j = 0; j < 4; ++j) {
            int r = wv * 4 + j;
            int cj = ncnt[r], off = nrp[r];
            int k = g;
            uint2 m = make_uint2(0, 0); u32 ev = 0;
            if (k < cj) {
                int s = slist[off + k];
                const u16* xr = src + (int64_t)s * D;
                m = *reinterpret_cast<const uint2*>(xr + hl * 4);
                if (D == 144) { if (hl < 8) ev = *reinterpret_cast<const u32*>(xr + 128 + hl * 2); }
            }
            while (k < cj) {
                int k2 = k + 2;
                uint2 m2 = make_uint2(0, 0); u32 ev2 = 0;
                if (k2 < cj) {
                    int s2 = slist[off + k2];
                    const u16* xr2 = src + (int64_t)s2 * D;
                    m2 = *reinterpret_cast<const uint2*>(xr2 + hl * 4);
                    if (D == 144) { if (hl < 8) ev2 = *reinterpret_cast<const u32*>(xr2 + 128 + hl * 2); }
                }
                acc[j][0] += b2f((u16)(m.x & 0xffffu));
                acc[j][1] += b2f((u16)(m.x >> 16));
                acc[j][2] += b2f((u16)(m.y & 0xffffu));
                acc[j][3] += b2f((u16)(m.y >> 16));
                if (D == 144) {
                    ecc[j][0] += b2f((u16)(ev & 0xffffu));
                    ecc[j][1] += b2f((u16)(ev >> 16));
                }
                m = m2; ev = ev2; k = k2;
            }
        }
    }

    // ---- cross-half reduce, write mean rows (bf16) at k offset 0
    #pragma unroll
    for (int j = 0; j < 4; ++j) {
        #pragma unroll
        for (int q = 0; q < 4; ++q) acc[j][q] += __shfl_xor(acc[j][q], 32, 64);
        if (D == 144) {
            ecc[j][0] += __shfl_xor(ecc[j][0], 32, 64);
            ecc[j][1] += __shfl_xor(ecc[j][1], 32, 64);
        }
        int r = wv * 4 + j;
        float rinv = 1.0f / fmaxf((float)ndeg[r], 1.0f);
        char* rowp = (char*)sAB + r * ROWB;
        if (lane < 32) {
            u32 lo = (u32)f2b(acc[j][0] * rinv) | ((u32)f2b(acc[j][1] * rinv) << 16);
            u32 hi = (u32)f2b(acc[j][2] * rinv) | ((u32)f2b(acc[j][3] * rinv) << 16);
            *reinterpret_cast<uint2*>(rowp + hl * 8) = make_uint2(lo, hi);
            if (D == 144) {
                if (hl < 8) {
                    u32 evo = (u32)f2b(ecc[j][0] * rinv) | ((u32)f2b(ecc[j][1] * rinv) << 16);
                    *reinterpret_cast<u32*>(rowp + 256 + hl * 4) = evo;
                }
            }
        }
    }
    __syncthreads();

    // ---- MFMA GEMM: wave wv covers n-tiles {2wv, 2wv+1}, all 16 rows, K=2D
    const int arow = lane & 15;
    const int kgrp = (lane >> 4) & 3;
    const int nt0 = wv * 2;
    f32x4 acc0 = {0.f, 0.f, 0.f, 0.f}, acc1 = {0.f, 0.f, 0.f, 0.f};
    for (int kt = 0; kt < KT; ++kt) {
        bf16x8 a = *reinterpret_cast<const bf16x8*>((char*)sAB + arow * ROWB + kt * 64 + kgrp * 16);
        bf16x8 b0 = *reinterpret_cast<const bf16x8*>(wp + ((size_t)(kt * 8 + nt0) * 64 + lane) * 8);
        bf16x8 b1 = *reinterpret_cast<const bf16x8*>(wp + ((size_t)(kt * 8 + nt0 + 1) * 64 + lane) * 8);
        acc0 = __builtin_amdgcn_mfma_f32_16x16x32_bf16(a, b0, acc0, 0, 0, 0);
        acc1 = __builtin_amdgcn_mfma_f32_16x16x32_bf16(a, b1, acc1, 0, 0, 0);
    }

    float bias0 = bl[nt0 * 16 + arow], bias1 = bl[nt0 * 16 + 16 + arow];
    if (!HEAD) {
        #pragma unroll
        for (int q = 0; q < 4; ++q) {
            int r = kgrp * 4 + q;
            if (r < nrows) {
                int64_t row = block0 + r;
                hout[row * 128 + nt0 * 16 + arow]      = f2b(fmaxf(acc0[q] + bias0, 0.f));
                hout[row * 128 + nt0 * 16 + 16 + arow] = f2b(fmaxf(acc1[q] + bias1, 0.f));
            }
        }
    } else {
        float w0 = Wseg[nt0 * 16 + arow], w1 = Wseg[nt0 * 16 + 16 + arow];
        float p[4];
        #pragma unroll
        for (int q = 0; q < 4; ++q) {
            int r = kgrp * 4 + q;
            const u16* selfrow = (const u16*)((char*)sAB + r * ROWB + D * 2);
            float v0 = fmaxf(acc0[q] + bias0, 0.f) + b2f(selfrow[nt0 * 16 + arow]);
            float v1 = fmaxf(acc1[q] + bias1, 0.f) + b2f(selfrow[nt0 * 16 + 16 + arow]);
            p[q] = v0 * w0 + v1 * w1;
        }
        #pragma unroll
        for (int off = 1; off < 16; off <<= 1) {
            p[0] += __shfl_xor(p[0], off, 64);
            p[1] += __shfl_xor(p[1], off, 64);
            p[2] += __shfl_xor(p[2], off, 64);
            p[3] += __shfl_xor(p[3], off, 64);
        }
        if (arow == 0) {
            #pragma unroll
            for (int q = 0; q < 4; ++q) ps[wv][kgrp * 4 + q] = p[q];
        }
        __syncthreads();
        if (tid < 16 && tid < nrows) {
            float s = ps[0][tid] + ps[1][tid] + ps[2][tid] + ps[3][tid];
            int64_t row = block0 + tid;
            if (ACCUM) dout[row] += s + linb[0];
            else dout[row] = s;
        }
    }
}

// ---------------------------------------------------------------- launch
extern "C" void kernel_launch(void* const* d_in, const int* in_sizes, int n_in,
                              void* d_out, int out_size, void* d_ws, size_t ws_size,
                              hipStream_t stream) {
    const float* x       = (const float*)d_in[0];
    const int*   edge_in = (const int*)d_in[1];
    const int*   edge_out= (const int*)d_in[2];
    const float* emb     = (const float*)d_in[3];
    const float* in1_Wl  = (const float*)d_in[4];
    const float* in1_bl  = (const float*)d_in[5];
    const float* in1_Wr  = (const float*)d_in[6];
    const float* in2_Wl  = (const float*)d_in[7];
    const float* in2_bl  = (const float*)d_in[8];
    const float* in2_Wr  = (const float*)d_in[9];
    const float* out1_Wl = (const float*)d_in[10];
    const float* out1_bl = (const float*)d_in[11];
    const float* out1_Wr = (const float*)d_in[12];
    const float* out2_Wl = (const float*)d_in[13];
    const float* out2_bl = (const float*)d_in[14];
    const float* out2_Wr = (const float*)d_in[15];
    const float* lin_W   = (const float*)d_in[16];
    const float* lin_b   = (const float*)d_in[17];

    const int N = in_sizes[0] / 128;
    const int E = in_sizes[1] / 2;
    const int nbk = (N + 15) / 16;                   // buckets = fused blocks
    const int nb = (nbk + SCAN_TILE - 1) / SCAN_TILE;

    char* wsb = (char*)d_ws;
    size_t off = 0;
    auto alloc = [&](size_t bytes) {
        char* p = wsb + off;
        off = (off + bytes + 255) & ~(size_t)255;
        return p;
    };
    int* brp   = (int*)alloc((size_t)(nbk + 1) * 4);
    int* btmp  = (int*)alloc((size_t)nbk * 4);
    int* bsum  = (int*)alloc((size_t)(nb + 1) * 4);
    u32* recs  = (u32*)alloc((size_t)E * 4);             //  6.4 MB
    u16* xb    = (u16*)alloc((size_t)N * 144 * 2);       // 28.8 MB
    u16* h1b   = (u16*)alloc((size_t)N * 128 * 2);       // 25.6 MB
    u16* wp_i1 = (u16*)alloc((size_t)288 * 128 * 2);
    u16* wp_i2 = (u16*)alloc((size_t)256 * 128 * 2);
    u16* wp_o1 = (u16*)alloc((size_t)288 * 128 * 2);
    u16* wp_o2 = (u16*)alloc((size_t)256 * 128 * 2);     // total ~62 MB

    build_xb_k<<<(N * 36 + 255) / 256, 256, 0, stream>>>(x, emb, xb, N);
    pack_w_k<144><<<18, 256, 0, stream>>>(in1_Wl, in1_Wr, wp_i1);
    pack_w_k<128><<<16, 256, 0, stream>>>(in2_Wl, in2_Wr, wp_i2);
    pack_w_k<144><<<18, 256, 0, stream>>>(out1_Wl, out1_Wr, wp_o1);
    pack_w_k<128><<<16, 256, 0, stream>>>(out2_Wl, out2_Wr, wp_o2);

    const int eg = (E + 255) / 256;
    const int fg = nbk;

    auto build_buckets = [&](const int* edge) {
        hipMemsetAsync(btmp, 0, (size_t)nbk * 4, stream);
        bcount_k<<<eg, 256, 0, stream>>>(edge, E, btmp);
        scan_sum_k<<<nb, 256, 0, stream>>>(btmp, nbk, bsum);
        scan_carry_k<<<1, 64, 0, stream>>>(bsum, nb, brp + nbk);
        scan_write_k<<<nb, 256, 0, stream>>>(btmp, nbk, bsum, brp);
        hipMemsetAsync(btmp, 0, (size_t)nbk * 4, stream);
        bscatter_k<<<eg, 256, 0, stream>>>(edge, E, brp, btmp, recs);
    };

    // ---- OUT direction: d_out = s_out
    build_buckets(edge_out);
    fused_sage<144, false, false><<<fg, 256, 0, stream>>>(xb, brp, recs, wp_o1, out1_bl,
            h1b, nullptr, nullptr, nullptr, N);
    fused_sage<128, true, false><<<fg, 256, 0, stream>>>(h1b, brp, recs, wp_o2, out2_bl,
            nullptr, (float*)d_out, lin_W + 128, lin_b, N);

    // ---- IN direction: d_out += s_in + b
    build_buckets(edge_in);
    fused_sage<144, false, false><<<fg, 256, 0, stream>>>(xb, brp, recs, wp_i1, in1_bl,
            h1b, nullptr, nullptr, nullptr, N);
    fused_sage<128, true, true><<<fg, 256, 0, stream>>>(h1b, brp, recs, wp_i2, in2_bl,
            nullptr, (float*)d_out, lin_W, lin_b, N);
}